// Round 1
// baseline (25.178 us; speedup 1.0000x reference)
//
#include <hip/hip_runtime.h>
#include <math.h>

#define N_BINS 100
#define N_CAP  2

__device__ __forceinline__ float sigmoidf(float x) {
    return 1.0f / (1.0f + expf(-x));
}

// One small block: compute the 200-entry LUT.
// LUT[cap*N_BINS + bin] = trust_temp(bin_centers[bin], cap)  (will folded into cap 0)
__global__ void RobotTrustModel_lut_kernel(
        const float* __restrict__ bin_centers,
        const float* __restrict__ pre_beta,
        const float* __restrict__ pre_can_l,
        const float* __restrict__ pre_can_u,
        const float* __restrict__ pre_will_l,
        const float* __restrict__ pre_will_u,
        float* __restrict__ lut) {
    int tid = threadIdx.x;
    if (tid >= N_CAP * N_BINS) return;
    int cap = tid / N_BINS;
    int bin = tid % N_BINS;

    float cl_raw = fminf(pre_can_l[cap], pre_can_u[cap]);
    float cu_raw = fmaxf(pre_can_l[cap], pre_can_u[cap]);
    float can_l = sigmoidf(cl_raw);
    float can_u = sigmoidf(cu_raw);

    float wl_raw = fminf(pre_will_l[0], pre_will_u[0]);
    float wu_raw = fmaxf(pre_will_l[0], pre_will_u[0]);
    float will = 0.5f * (sigmoidf(wl_raw) + sigmoidf(wu_raw));

    float beta  = pre_beta[cap] * pre_beta[cap];
    float denom = can_u - can_l;
    float p     = bin_centers[bin];

    float t;
    if (beta < -50.0f) {
        t = 1.0f - (1.0f / (beta * denom)) *
            (log1pf(expf(beta * (p - can_l))) - log1pf(expf(beta * (p - can_u))));
    } else {
        t = (p <= can_l) ? 1.0f
          : ((p > can_u) ? 0.0f
          : (can_u - p) / (denom + 1e-4f));
    }
    if (cap == 0) t *= will;
    lut[cap * N_BINS + bin] = t;
}

// Main kernel: int4 load = 2 rows of indices per thread; LUT gather from LDS;
// float2 store. Pure memory-bound streaming.
__global__ __launch_bounds__(256) void RobotTrustModel_trust_kernel(
        const int4* __restrict__ idx,
        const float* __restrict__ lut,
        float2* __restrict__ out,
        int n_pairs) {
    __shared__ float slut[N_CAP * N_BINS];
    for (int i = threadIdx.x; i < N_CAP * N_BINS; i += blockDim.x)
        slut[i] = lut[i];
    __syncthreads();

    int t      = blockIdx.x * blockDim.x + threadIdx.x;
    int stride = gridDim.x * blockDim.x;
    for (; t < n_pairs; t += stride) {
        int4 v = idx[t];
        float a = slut[v.x] * slut[N_BINS + v.y];
        float b = slut[v.z] * slut[N_BINS + v.w];
        out[t] = make_float2(a, b);
    }
}

extern "C" void kernel_launch(void* const* d_in, const int* in_sizes, int n_in,
                              void* d_out, int out_size, void* d_ws, size_t ws_size,
                              hipStream_t stream) {
    const float* bin_centers = (const float*)d_in[0];
    const int*   obs_idx     = (const int*)d_in[1];
    const float* pre_beta    = (const float*)d_in[2];
    const float* pre_can_l   = (const float*)d_in[3];
    const float* pre_can_u   = (const float*)d_in[4];
    const float* pre_will_l  = (const float*)d_in[5];
    const float* pre_will_u  = (const float*)d_in[6];

    float* lut = (float*)d_ws;               // 200 floats
    float* out = (float*)d_out;

    int n_diffs = in_sizes[1] / N_CAP;       // 8388608
    int n_pairs = n_diffs / 2;               // 2 rows per thread via int4

    RobotTrustModel_lut_kernel<<<1, 256, 0, stream>>>(
        bin_centers, pre_beta, pre_can_l, pre_can_u, pre_will_l, pre_will_u, lut);

    int block = 256;
    int grid  = 2048;                        // grid-stride; ~8 iters/thread
    RobotTrustModel_trust_kernel<<<grid, block, 0, stream>>>(
        (const int4*)obs_idx, lut, (float2*)out, n_pairs);
}

// Round 2
// 21.500 us; speedup vs baseline: 1.1711x; 1.1711x over previous
//
#include <hip/hip_runtime.h>
#include <math.h>

#define N_BINS 100
#define N_CAP  2

__device__ __forceinline__ float sigmoidf(float x) {
    return 1.0f / (1.0f + expf(-x));
}

// Fused: each block computes the 200-entry LUT (cheap, hidden), then streams.
// LUT[cap*N_BINS + bin] = trust_temp(bin_centers[bin], cap); will folded into cap 0.
__global__ __launch_bounds__(256) void RobotTrustModel_trust_kernel(
        const float* __restrict__ bin_centers,
        const float* __restrict__ pre_beta,
        const float* __restrict__ pre_can_l,
        const float* __restrict__ pre_can_u,
        const float* __restrict__ pre_will_l,
        const float* __restrict__ pre_will_u,
        const int4*  __restrict__ idx,
        float2*      __restrict__ out,
        int n_pairs) {
    __shared__ float slut[N_CAP * N_BINS];

    int tid = threadIdx.x;
    if (tid < N_CAP * N_BINS) {
        int cap = tid / N_BINS;
        int bin = tid % N_BINS;

        float cl_raw = fminf(pre_can_l[cap], pre_can_u[cap]);
        float cu_raw = fmaxf(pre_can_l[cap], pre_can_u[cap]);
        float can_l = sigmoidf(cl_raw);
        float can_u = sigmoidf(cu_raw);

        float wl_raw = fminf(pre_will_l[0], pre_will_u[0]);
        float wu_raw = fmaxf(pre_will_l[0], pre_will_u[0]);
        float will = 0.5f * (sigmoidf(wl_raw) + sigmoidf(wu_raw));

        float beta  = pre_beta[cap] * pre_beta[cap];
        float denom = can_u - can_l;
        float p     = bin_centers[bin];

        float t;
        if (beta < -50.0f) {
            t = 1.0f - (1.0f / (beta * denom)) *
                (log1pf(expf(beta * (p - can_l))) - log1pf(expf(beta * (p - can_u))));
        } else {
            t = (p <= can_l) ? 1.0f
              : ((p > can_u) ? 0.0f
              : (can_u - p) / (denom + 1e-4f));
        }
        if (cap == 0) t *= will;
        slut[cap * N_BINS + bin] = t;
    }
    __syncthreads();

    int t      = blockIdx.x * blockDim.x + tid;
    int stride = gridDim.x * blockDim.x;
    for (; t < n_pairs; t += stride) {
        int4 v = idx[t];
        float a = slut[v.x] * slut[N_BINS + v.y];
        float b = slut[v.z] * slut[N_BINS + v.w];
        out[t] = make_float2(a, b);
    }
}

extern "C" void kernel_launch(void* const* d_in, const int* in_sizes, int n_in,
                              void* d_out, int out_size, void* d_ws, size_t ws_size,
                              hipStream_t stream) {
    const float* bin_centers = (const float*)d_in[0];
    const int*   obs_idx     = (const int*)d_in[1];
    const float* pre_beta    = (const float*)d_in[2];
    const float* pre_can_l   = (const float*)d_in[3];
    const float* pre_can_u   = (const float*)d_in[4];
    const float* pre_will_l  = (const float*)d_in[5];
    const float* pre_will_u  = (const float*)d_in[6];

    float* out = (float*)d_out;

    int n_diffs = in_sizes[1] / N_CAP;       // 8388608
    int n_pairs = n_diffs / 2;               // 4194304: 2 rows per thread via int4

    int block = 256;
    int grid  = 4096;                        // 4 grid-stride iters/thread
    RobotTrustModel_trust_kernel<<<grid, block, 0, stream>>>(
        bin_centers, pre_beta, pre_can_l, pre_can_u, pre_will_l, pre_will_u,
        (const int4*)obs_idx, (float2*)out, n_pairs);
}